// Round 2
// baseline (424.687 us; speedup 1.0000x reference)
//
#include <hip/hip_runtime.h>

#define LQN 2046
#define LL  2048
#define CC  512
#define DD  64

typedef float  f32x4 __attribute__((ext_vector_type(4)));
typedef float  f32x2 __attribute__((ext_vector_type(2)));
typedef __bf16 b16x8 __attribute__((ext_vector_type(8)));
typedef unsigned int u32x4 __attribute__((ext_vector_type(4)));

static __device__ __forceinline__ unsigned short f2bf(float f) {
  union { float f; unsigned u; } v; v.f = f;
  return (unsigned short)((v.u + 0x7fffu + ((v.u >> 16) & 1u)) >> 16);
}

static __device__ __forceinline__ f32x4 mfma16(b16x8 a, b16x8 b, f32x4 c) {
  return __builtin_amdgcn_mfma_f32_16x16x32_bf16(a, b, c, 0, 0, 0);
}

// ---------------- Kernel 1: grouped-conv QKV projections (MFMA) --------------
__global__ __launch_bounds__(256) void conv_qkv_kernel(
    const float* __restrict__ in, const float* __restrict__ qw,
    const float* __restrict__ kw, const float* __restrict__ vw,
    unsigned short* __restrict__ qo, unsigned short* __restrict__ ko,
    unsigned short* __restrict__ vo)
{
  __shared__ __align__(16) unsigned short inT[130 * 72];  // [t][ci] bf16, pad 72
  __shared__ __align__(16) unsigned short buf[128 * 72];  // transpose buffer

  const int tile = blockIdx.x, g = blockIdx.y, b = blockIdx.z;
  const int t0 = tile * 128;
  const int tid = threadIdx.x;
  const int lane = tid & 63;
  const int wv = tid >> 6;
  const int r0 = lane & 15, qh = lane >> 4;

  {
    const int ci = tid & 63, ch = tid >> 6;
    const float* src = in + ((size_t)(b * CC + g * 64 + ci)) * LL;
    #pragma unroll
    for (int i = 0; i < 8; ++i) {
      int t = ch * 32 + i * 4;
      f32x4 d = *(const f32x4*)(src + t0 + t);
      inT[(t + 0) * 72 + ci] = f2bf(d.x);
      inT[(t + 1) * 72 + ci] = f2bf(d.y);
      inT[(t + 2) * 72 + ci] = f2bf(d.z);
      inT[(t + 3) * 72 + ci] = f2bf(d.w);
    }
    if (ch == 0) {
      #pragma unroll
      for (int e = 0; e < 2; ++e) {
        int t = 128 + e;
        int tg = t0 + t; if (tg > LL - 1) tg = LL - 1;
        inT[t * 72 + ci] = f2bf(src[tg]);
      }
    }
  }
  __syncthreads();

  const float* wptr[3] = {qw, kw, vw};
  const f32x4 zero4 = {0.f, 0.f, 0.f, 0.f};

  for (int p = 0; p < 3; ++p) {
    b16x8 aW[6];
    {
      const float* wb = wptr[p] + (size_t)(g * 64 + wv * 16 + r0) * 192;
      #pragma unroll
      for (int kc = 0; kc < 6; ++kc) {
        const int ktap = kc >> 1;
        const int cib = (kc & 1) * 32 + qh * 8;
        union { b16x8 v; unsigned short u[8]; } fr;
        #pragma unroll
        for (int j = 0; j < 8; ++j)
          fr.u[j] = f2bf(wb[(cib + j) * 3 + ktap]);
        aW[kc] = fr.v;
      }
    }
    f32x4 acc[8];
    #pragma unroll
    for (int nt = 0; nt < 8; ++nt) acc[nt] = zero4;
    #pragma unroll
    for (int kc = 0; kc < 6; ++kc) {
      const int radd = kc >> 1;
      const int colh = (kc & 1) * 32 + qh * 8;
      #pragma unroll
      for (int nt = 0; nt < 8; ++nt) {
        const int trow = nt * 16 + r0 + radd;
        b16x8 bI = *(const b16x8*)&inT[trow * 72 + colh];
        acc[nt] = mfma16(aW[kc], bI, acc[nt]);
      }
    }
    __syncthreads();
    if (p < 2) {
      #pragma unroll
      for (int nt = 0; nt < 8; ++nt) {
        const int t = nt * 16 + r0;
        #pragma unroll
        for (int r = 0; r < 4; ++r)
          buf[t * 72 + wv * 16 + qh * 4 + r] = f2bf(acc[nt][r]);
      }
      __syncthreads();
      unsigned short* dst = (p == 0 ? qo : ko) +
          ((size_t)(b * 8 + g) * LQN + t0) * DD;
      #pragma unroll
      for (int it = 0; it < 4; ++it) {
        const int id = it * 256 + tid;
        const int t = id >> 3, c8 = id & 7;
        if (t0 + t < LQN)
          *(u32x4*)(dst + t * DD + c8 * 8) = *(const u32x4*)&buf[t * 72 + c8 * 8];
      }
    } else {
      #pragma unroll
      for (int nt = 0; nt < 8; ++nt) {
        const int t = nt * 16 + r0;
        #pragma unroll
        for (int r = 0; r < 4; ++r)
          buf[(wv * 16 + qh * 4 + r) * 136 + t] = f2bf(acc[nt][r]);
      }
      __syncthreads();
      unsigned short* dst = vo + ((size_t)(b * CC + g * 64)) * LL + t0;
      #pragma unroll
      for (int it = 0; it < 4; ++it) {
        const int id = it * 256 + tid;
        const int row = id >> 4, c16 = id & 15;
        *(u32x4*)(dst + (size_t)row * LL + c16 * 8) =
            *(const u32x4*)&buf[row * 136 + c16 * 8];
      }
    }
    __syncthreads();
  }
}

// ---------------- Kernel 2: causal flash attention + residual ----------------
// Causal pairing: block pi owns Q-tiles hi=31-pi and lo=pi -> exactly 33
// tile-computes per block, K/V staging shared. 1024 equal blocks = 4/CU,
// all resident. Next-tile K/V prefetched into regs; pre-compute barrier is
// raw s_barrier + lgkmcnt(0) only (no vmcnt drain).
__global__ __launch_bounds__(256, 4) void attn_kernel(
    const unsigned short* __restrict__ qg, const unsigned short* __restrict__ kg,
    const unsigned short* __restrict__ vg, const float* __restrict__ initw,
    float* __restrict__ out)
{
  __shared__ __align__(16) unsigned char smem[24576];
  unsigned short* Kl = (unsigned short*)smem;            // 8 KB
  unsigned short* Vl = (unsigned short*)(smem + 8192);   // 8 KB
  const int pi = blockIdx.x;            // 0..15
  const int hi = 31 - pi, lo = pi;      // paired Q-tiles
  const int bh = blockIdx.y;
  const int b = bh >> 3, h = bh & 7;
  const int tid = threadIdx.x, lane = tid & 63, wv = tid >> 6;
  const int r0 = lane & 15, qh = lane >> 4;
  unsigned short* Pl = (unsigned short*)(smem + 16384) + wv * 1024;

  const size_t kqbase = (size_t)bh * LQN * DD;
  const size_t vbase  = ((size_t)(b * CC + h * 64)) * LL;

  // Q fragments for both tiles
  b16x8 aQ0h, aQ1h, aQ0l, aQ1l;
  {
    int qrow = hi * 64 + wv * 16 + r0; if (qrow > LQN - 1) qrow = LQN - 1;
    const unsigned short* qp = qg + kqbase + (size_t)qrow * DD;
    aQ0h = *(const b16x8*)(qp + qh * 8);
    aQ1h = *(const b16x8*)(qp + 32 + qh * 8);
    qrow = lo * 64 + wv * 16 + r0;
    qp = qg + kqbase + (size_t)qrow * DD;
    aQ0l = *(const b16x8*)(qp + qh * 8);
    aQ1l = *(const b16x8*)(qp + 32 + qh * 8);
  }

  const f32x4 zero4 = {0.f, 0.f, 0.f, 0.f};
  f32x4 oh[4], ol[4];
  float mh[4], ml[4], lh[4], llr[4];
  #pragma unroll
  for (int dt = 0; dt < 4; ++dt) { oh[dt] = zero4; ol[dt] = zero4; }
  #pragma unroll
  for (int r = 0; r < 4; ++r) { mh[r] = -1e30f; ml[r] = -1e30f; lh[r] = 0.f; llr[r] = 0.f; }
  const float SCL = 0.51006979f;  // log2(e)/sqrt(8)

  // staging thread mapping
  const int strow = tid >> 3, stc = tid & 7;
  const int ssw = (strow & 7);
  u32x4 kR0, kR1, vR0, vR1;   // prefetch registers

  auto issue = [&](int kt) {
    const int kv0 = kt * 64;
    int sr0 = kv0 + strow;      if (sr0 > LQN - 1) sr0 = LQN - 1;
    int sr1 = kv0 + 32 + strow; if (sr1 > LQN - 1) sr1 = LQN - 1;
    kR0 = *(const u32x4*)(kg + kqbase + (size_t)sr0 * DD + stc * 8);
    kR1 = *(const u32x4*)(kg + kqbase + (size_t)sr1 * DD + stc * 8);
    vR0 = *(const u32x4*)(vg + vbase + (size_t)strow * LL + kv0 + stc * 8);
    vR1 = *(const u32x4*)(vg + vbase + (size_t)(32 + strow) * LL + kv0 + stc * 8);
  };
  auto store_lds = [&]() {
    *(u32x4*)(Kl + strow * 64 + ((stc ^ ssw) * 8))        = kR0;
    *(u32x4*)(Kl + (32 + strow) * 64 + ((stc ^ ssw) * 8)) = kR1;
    *(u32x4*)(Vl + strow * 64 + ((stc ^ ssw) * 8))        = vR0;
    *(u32x4*)(Vl + (32 + strow) * 64 + ((stc ^ ssw) * 8)) = vR1;
  };

  auto compute = [&](int qt, int kt, b16x8 aQ0, b16x8 aQ1,
                     f32x4 (&o)[4], float (&mrow)[4], float (&lrow)[4]) {
    const int kv0 = kt * 64;
    const bool diag = (kt == qt);
    const int ntmax = diag ? wv : 3;
    f32x4 s[4];
    #pragma unroll
    for (int nt = 0; nt < 4; ++nt) s[nt] = zero4;
    for (int nt = 0; nt <= ntmax; ++nt) {       // S = Q K^T
      const int krow = nt * 16 + r0;
      const unsigned short* kr = Kl + krow * 64;
      const int sw = krow & 7;
      b16x8 b0 = *(const b16x8*)(kr + ((qh ^ sw) * 8));
      b16x8 b1 = *(const b16x8*)(kr + (((4 + qh) ^ sw) * 8));
      s[nt] = mfma16(aQ0, b0, s[nt]);
      s[nt] = mfma16(aQ1, b1, s[nt]);
    }
    #pragma unroll
    for (int nt = 0; nt < 4; ++nt) s[nt] *= SCL;
    if (diag) {
      #pragma unroll
      for (int nt = 0; nt < 4; ++nt) {
        if (nt > ntmax) {
          s[nt] = (f32x4){-1e30f, -1e30f, -1e30f, -1e30f};
        } else {
          #pragma unroll
          for (int r = 0; r < 4; ++r) {
            const int rowg = qt * 64 + wv * 16 + qh * 4 + r;
            const int colg = kv0 + nt * 16 + r0;
            if (colg > rowg) s[nt][r] = -1e30f;
          }
        }
      }
    }
    f32x4 corrv;
    #pragma unroll
    for (int r = 0; r < 4; ++r) {
      float s0 = s[0][r], s1 = s[1][r], s2 = s[2][r], s3 = s[3][r];
      float mt = fmaxf(fmaxf(s0, s1), fmaxf(s2, s3));
      #pragma unroll
      for (int mm = 1; mm <= 8; mm <<= 1) mt = fmaxf(mt, __shfl_xor(mt, mm));
      const float mn = fmaxf(mrow[r], mt);
      const float corr = __builtin_amdgcn_exp2f(mrow[r] - mn);
      mrow[r] = mn;
      const float p0 = __builtin_amdgcn_exp2f(s0 - mn);
      const float p1 = __builtin_amdgcn_exp2f(s1 - mn);
      const float p2 = __builtin_amdgcn_exp2f(s2 - mn);
      const float p3 = __builtin_amdgcn_exp2f(s3 - mn);
      float ps = p0 + p1 + p2 + p3;
      #pragma unroll
      for (int mm = 1; mm <= 8; mm <<= 1) ps += __shfl_xor(ps, mm);
      lrow[r] = lrow[r] * corr + ps;
      corrv[r] = corr;
      const int rl = qh * 4 + r;
      const int sw = rl & 7;
      unsigned short* pw = Pl + rl * 64;
      pw[(((r0) >> 3) ^ sw) * 8 + (r0 & 7)]      = f2bf(p0);
      pw[(((16 + r0) >> 3) ^ sw) * 8 + (r0 & 7)] = f2bf(p1);
      pw[(((32 + r0) >> 3) ^ sw) * 8 + (r0 & 7)] = f2bf(p2);
      pw[(((48 + r0) >> 3) ^ sw) * 8 + (r0 & 7)] = f2bf(p3);
    }
    #pragma unroll
    for (int dt = 0; dt < 4; ++dt) o[dt] *= corrv;
    #pragma unroll
    for (int kc = 0; kc < 2; ++kc) {
      b16x8 aP = *(const b16x8*)(Pl + r0 * 64 + (((kc * 4 + qh) ^ (r0 & 7)) * 8));
      #pragma unroll
      for (int dt = 0; dt < 4; ++dt) {
        const int vrow = dt * 16 + r0;
        b16x8 bv = *(const b16x8*)(Vl + vrow * 64 + (((kc * 4 + qh) ^ (vrow & 7)) * 8));
        o[dt] = mfma16(aP, bv, o[dt]);
      }
    }
  };

  issue(0);
  for (int kt = 0; kt <= hi; ++kt) {
    __syncthreads();                 // prev LDS reads consumed; drains old loads (already landed)
    store_lds();                     // RAW on prefetch regs -> compiler waits vmcnt
    if (kt < hi) issue(kt + 1);      // next tile in flight across the barrier
    asm volatile("s_waitcnt lgkmcnt(0)" ::: "memory");
    __builtin_amdgcn_s_barrier();    // no vmcnt drain here
    asm volatile("" ::: "memory");
    compute(hi, kt, aQ0h, aQ1h, oh, mh, lh);
    if (kt <= lo) compute(lo, kt, aQ0l, aQ1l, ol, ml, llr);
  }

  auto epilogue = [&](int qt, f32x4 (&o)[4], float (&lrow)[4]) {
    __syncthreads();
    float* initL = (float*)smem;     // [64 c][65]
    const int cc = tid >> 2, qgrp = (tid & 3) * 16;
    const float* src = initw + (size_t)(b * CC + h * 64 + cc) * LQN;
    #pragma unroll
    for (int u = 0; u < 8; ++u) {
      int col = qt * 64 + qgrp + u * 2;
      if (col > LQN - 2) col = LQN - 2;
      f32x2 d = *(const f32x2*)(src + col);
      initL[cc * 65 + qgrp + u * 2]     = d.x;
      initL[cc * 65 + qgrp + u * 2 + 1] = d.y;
    }
    __syncthreads();
    #pragma unroll
    for (int r = 0; r < 4; ++r) {
      const int ql = wv * 16 + qh * 4 + r;
      const int qgl = qt * 64 + ql;
      if (qgl >= LQN) continue;
      const float invl = 1.0f / lrow[r];
      float* dst = out + ((size_t)(b * LQN + qgl)) * CC + h * 64;
      #pragma unroll
      for (int dt = 0; dt < 4; ++dt)
        dst[dt * 16 + r0] = o[dt][r] * invl + initL[(dt * 16 + r0) * 65 + ql];
    }
  };
  epilogue(hi, oh, lh);
  epilogue(lo, ol, llr);
}

// ---------------- Kernel 3: LayerNorm over C, in-place on d_out --------------
__global__ __launch_bounds__(256) void ln_kernel(
    const float* __restrict__ gamma, const float* __restrict__ beta,
    float* __restrict__ out)
{
  const int row = blockIdx.x * 4 + ((int)threadIdx.x >> 6);
  const int lane = threadIdx.x & 63;
  if (row >= 8 * LQN) return;
  float* p = out + (size_t)row * CC;
  f32x4 x0 = *(const f32x4*)(p + lane * 8);
  f32x4 x1 = *(const f32x4*)(p + lane * 8 + 4);
  float s  = x0.x + x0.y + x0.z + x0.w + x1.x + x1.y + x1.z + x1.w;
  float sq = x0.x*x0.x + x0.y*x0.y + x0.z*x0.z + x0.w*x0.w
           + x1.x*x1.x + x1.y*x1.y + x1.z*x1.z + x1.w*x1.w;
  #pragma unroll
  for (int mm = 1; mm <= 32; mm <<= 1) {
    s  += __shfl_xor(s, mm);
    sq += __shfl_xor(sq, mm);
  }
  const float mu = s * (1.f / 512.f);
  const float var = sq * (1.f / 512.f) - mu * mu;
  const float rstd = rsqrtf(var + 1e-5f);
  f32x4 g0 = *(const f32x4*)(gamma + lane * 8);
  f32x4 g1 = *(const f32x4*)(gamma + lane * 8 + 4);
  f32x4 b0 = *(const f32x4*)(beta + lane * 8);
  f32x4 b1 = *(const f32x4*)(beta + lane * 8 + 4);
  x0 = (x0 - mu) * rstd * g0 + b0;
  x1 = (x1 - mu) * rstd * g1 + b1;
  *(f32x4*)(p + lane * 8)     = x0;
  *(f32x4*)(p + lane * 8 + 4) = x1;
}

extern "C" void kernel_launch(void* const* d_in, const int* in_sizes, int n_in,
                              void* d_out, int out_size, void* d_ws, size_t ws_size,
                              hipStream_t stream)
{
  const float* input = (const float*)d_in[0];
  const float* initw = (const float*)d_in[1];
  const float* qw    = (const float*)d_in[2];
  const float* kw    = (const float*)d_in[3];
  const float* vw    = (const float*)d_in[4];
  const float* gamma = (const float*)d_in[5];
  const float* beta  = (const float*)d_in[6];
  float* outp = (float*)d_out;

  unsigned short* q = (unsigned short*)d_ws;
  unsigned short* k = q + (16u * 1024u * 1024u / 2u);
  unsigned short* v = q + (32u * 1024u * 1024u / 2u);

  hipLaunchKernelGGL(conv_qkv_kernel, dim3(16, 8, 8), dim3(256), 0, stream,
                     input, qw, kw, vw, q, k, v);
  hipLaunchKernelGGL(attn_kernel, dim3(16, 64), dim3(256), 0, stream,
                     q, k, v, initw, outp);
  hipLaunchKernelGGL(ln_kernel, dim3(4092), dim3(256), 0, stream,
                     gamma, beta, outp);
}

// Round 3
// 335.708 us; speedup vs baseline: 1.2651x; 1.2651x over previous
//
#include <hip/hip_runtime.h>

#define LQN 2046
#define LL  2048
#define CC  512
#define DD  64

typedef float  f32x4 __attribute__((ext_vector_type(4)));
typedef float  f32x2 __attribute__((ext_vector_type(2)));
typedef __bf16 b16x8 __attribute__((ext_vector_type(8)));
typedef unsigned int u32x4 __attribute__((ext_vector_type(4)));

static __device__ __forceinline__ unsigned short f2bf(float f) {
  union { float f; unsigned u; } v; v.f = f;
  return (unsigned short)((v.u + 0x7fffu + ((v.u >> 16) & 1u)) >> 16);
}

static __device__ __forceinline__ f32x4 mfma16(b16x8 a, b16x8 b, f32x4 c) {
  return __builtin_amdgcn_mfma_f32_16x16x32_bf16(a, b, c, 0, 0, 0);
}

// async global->LDS, 16B per lane; LDS dest = wave-uniform base + lane*16
static __device__ __forceinline__ void glds16(const unsigned short* g, unsigned short* l) {
  __builtin_amdgcn_global_load_lds(
      (const __attribute__((address_space(1))) unsigned int*)(g),
      (__attribute__((address_space(3))) unsigned int*)(l),
      16, 0, 0);
}

// ---------------- Kernel 1: grouped-conv QKV projections (MFMA) --------------
__global__ __launch_bounds__(256) void conv_qkv_kernel(
    const float* __restrict__ in, const float* __restrict__ qw,
    const float* __restrict__ kw, const float* __restrict__ vw,
    unsigned short* __restrict__ qo, unsigned short* __restrict__ ko,
    unsigned short* __restrict__ vo)
{
  __shared__ __align__(16) unsigned short inT[130 * 72];  // [t][ci] bf16, pad 72
  __shared__ __align__(16) unsigned short buf[128 * 72];  // transpose buffer

  const int tile = blockIdx.x, g = blockIdx.y, b = blockIdx.z;
  const int t0 = tile * 128;
  const int tid = threadIdx.x;
  const int lane = tid & 63;
  const int wv = tid >> 6;
  const int r0 = lane & 15, qh = lane >> 4;

  {
    const int ci = tid & 63, ch = tid >> 6;
    const float* src = in + ((size_t)(b * CC + g * 64 + ci)) * LL;
    #pragma unroll
    for (int i = 0; i < 8; ++i) {
      int t = ch * 32 + i * 4;
      f32x4 d = *(const f32x4*)(src + t0 + t);
      inT[(t + 0) * 72 + ci] = f2bf(d.x);
      inT[(t + 1) * 72 + ci] = f2bf(d.y);
      inT[(t + 2) * 72 + ci] = f2bf(d.z);
      inT[(t + 3) * 72 + ci] = f2bf(d.w);
    }
    if (ch == 0) {
      #pragma unroll
      for (int e = 0; e < 2; ++e) {
        int t = 128 + e;
        int tg = t0 + t; if (tg > LL - 1) tg = LL - 1;
        inT[t * 72 + ci] = f2bf(src[tg]);
      }
    }
  }
  __syncthreads();

  const float* wptr[3] = {qw, kw, vw};
  const f32x4 zero4 = {0.f, 0.f, 0.f, 0.f};

  for (int p = 0; p < 3; ++p) {
    b16x8 aW[6];
    {
      const float* wb = wptr[p] + (size_t)(g * 64 + wv * 16 + r0) * 192;
      #pragma unroll
      for (int kc = 0; kc < 6; ++kc) {
        const int ktap = kc >> 1;
        const int cib = (kc & 1) * 32 + qh * 8;
        union { b16x8 v; unsigned short u[8]; } fr;
        #pragma unroll
        for (int j = 0; j < 8; ++j)
          fr.u[j] = f2bf(wb[(cib + j) * 3 + ktap]);
        aW[kc] = fr.v;
      }
    }
    f32x4 acc[8];
    #pragma unroll
    for (int nt = 0; nt < 8; ++nt) acc[nt] = zero4;
    #pragma unroll
    for (int kc = 0; kc < 6; ++kc) {
      const int radd = kc >> 1;
      const int colh = (kc & 1) * 32 + qh * 8;
      #pragma unroll
      for (int nt = 0; nt < 8; ++nt) {
        const int trow = nt * 16 + r0 + radd;
        b16x8 bI = *(const b16x8*)&inT[trow * 72 + colh];
        acc[nt] = mfma16(aW[kc], bI, acc[nt]);
      }
    }
    __syncthreads();
    if (p < 2) {
      #pragma unroll
      for (int nt = 0; nt < 8; ++nt) {
        const int t = nt * 16 + r0;
        #pragma unroll
        for (int r = 0; r < 4; ++r)
          buf[t * 72 + wv * 16 + qh * 4 + r] = f2bf(acc[nt][r]);
      }
      __syncthreads();
      unsigned short* dst = (p == 0 ? qo : ko) +
          ((size_t)(b * 8 + g) * LQN + t0) * DD;
      #pragma unroll
      for (int it = 0; it < 4; ++it) {
        const int id = it * 256 + tid;
        const int t = id >> 3, c8 = id & 7;
        if (t0 + t < LQN)
          *(u32x4*)(dst + t * DD + c8 * 8) = *(const u32x4*)&buf[t * 72 + c8 * 8];
      }
    } else {
      #pragma unroll
      for (int nt = 0; nt < 8; ++nt) {
        const int t = nt * 16 + r0;
        #pragma unroll
        for (int r = 0; r < 4; ++r)
          buf[(wv * 16 + qh * 4 + r) * 136 + t] = f2bf(acc[nt][r]);
      }
      __syncthreads();
      unsigned short* dst = vo + ((size_t)(b * CC + g * 64)) * LL + t0;
      #pragma unroll
      for (int it = 0; it < 4; ++it) {
        const int id = it * 256 + tid;
        const int row = id >> 4, c16 = id & 15;
        *(u32x4*)(dst + (size_t)row * LL + c16 * 8) =
            *(const u32x4*)&buf[row * 136 + c16 * 8];
      }
    }
    __syncthreads();
  }
}

// ---------------- attention tile compute (forced inline) ---------------------
static __device__ __forceinline__ void attn_tile(
    const unsigned short* __restrict__ Kl, const unsigned short* __restrict__ Vl,
    unsigned short* __restrict__ Pl,
    int qt, int kt, int wv, int r0, int qh,
    b16x8 aQ0, b16x8 aQ1,
    f32x4 (&o)[4], float (&mrow)[4], float (&lrow)[4])
{
  const float SCL = 0.51006979f;  // log2(e)/sqrt(8)
  f32x4 s[4];
  #pragma unroll
  for (int nt = 0; nt < 4; ++nt) {            // S = Q K^T (always 4 row-tiles)
    const int krow = nt * 16 + r0;
    const unsigned short* kr = Kl + krow * 64;
    const int sw = krow & 7;
    b16x8 b0 = *(const b16x8*)(kr + ((qh ^ sw) * 8));
    b16x8 b1 = *(const b16x8*)(kr + (((4 + qh) ^ sw) * 8));
    f32x4 acc = {0.f, 0.f, 0.f, 0.f};
    acc = mfma16(aQ0, b0, acc);
    acc = mfma16(aQ1, b1, acc);
    s[nt] = acc * SCL;
  }
  if (kt == qt) {                             // causal mask (local coords)
    #pragma unroll
    for (int nt = 0; nt < 4; ++nt) {
      #pragma unroll
      for (int r = 0; r < 4; ++r) {
        const int rowl = wv * 16 + qh * 4 + r;
        const int coll = nt * 16 + r0;
        if (coll > rowl) s[nt][r] = -1e30f;
      }
    }
  }
  f32x4 corrv;
  #pragma unroll
  for (int r = 0; r < 4; ++r) {
    float s0 = s[0][r], s1 = s[1][r], s2 = s[2][r], s3 = s[3][r];
    float mt = fmaxf(fmaxf(s0, s1), fmaxf(s2, s3));
    #pragma unroll
    for (int mm = 1; mm <= 8; mm <<= 1) mt = fmaxf(mt, __shfl_xor(mt, mm));
    const float mn = fmaxf(mrow[r], mt);
    const float corr = __builtin_amdgcn_exp2f(mrow[r] - mn);
    mrow[r] = mn;
    const float p0 = __builtin_amdgcn_exp2f(s0 - mn);
    const float p1 = __builtin_amdgcn_exp2f(s1 - mn);
    const float p2 = __builtin_amdgcn_exp2f(s2 - mn);
    const float p3 = __builtin_amdgcn_exp2f(s3 - mn);
    float ps = p0 + p1 + p2 + p3;
    #pragma unroll
    for (int mm = 1; mm <= 8; mm <<= 1) ps += __shfl_xor(ps, mm);
    lrow[r] = lrow[r] * corr + ps;
    corrv[r] = corr;
    const int rl = qh * 4 + r;
    const int sw = rl & 7;
    unsigned short* pw = Pl + rl * 64;
    pw[((r0 >> 3) ^ sw) * 8 + (r0 & 7)]        = f2bf(p0);
    pw[(((16 + r0) >> 3) ^ sw) * 8 + (r0 & 7)] = f2bf(p1);
    pw[(((32 + r0) >> 3) ^ sw) * 8 + (r0 & 7)] = f2bf(p2);
    pw[(((48 + r0) >> 3) ^ sw) * 8 + (r0 & 7)] = f2bf(p3);
  }
  #pragma unroll
  for (int dt = 0; dt < 4; ++dt) o[dt] *= corrv;
  #pragma unroll
  for (int kc = 0; kc < 2; ++kc) {            // O += P V
    b16x8 aP = *(const b16x8*)(Pl + r0 * 64 + (((kc * 4 + qh) ^ (r0 & 7)) * 8));
    #pragma unroll
    for (int dt = 0; dt < 4; ++dt) {
      const int vrow = dt * 16 + r0;
      b16x8 bv = *(const b16x8*)(Vl + vrow * 64 + (((kc * 4 + qh) ^ (vrow & 7)) * 8));
      o[dt] = mfma16(aP, bv, o[dt]);
    }
  }
}

static __device__ __forceinline__ void issue_tile(
    const unsigned short*& kSrc, const unsigned short*& vSrc,
    unsigned short* kDst, unsigned short* vDst)
{
  glds16(kSrc,          kDst);
  glds16(kSrc + 8 * DD, kDst + 512);
  glds16(vSrc,          vDst);
  glds16(vSrc + 8 * LL, vDst + 512);
  kSrc += 64 * DD;   // next kv tile: +64 rows
  vSrc += 64;        // next kv tile: +64 columns
}

static __device__ __forceinline__ void attn_epilogue(
    unsigned short* smem, const float* __restrict__ initw,
    float* __restrict__ out, int b, int h, int qt,
    int tid, int wv, int r0, int qh,
    f32x4 (&o)[4], float (&lrow)[4])
{
  __syncthreads();
  float* initL = (float*)smem;     // [64 c][65]
  const int cc = tid >> 2, qgrp = (tid & 3) * 16;
  const float* src = initw + (size_t)(b * CC + h * 64 + cc) * LQN;
  #pragma unroll
  for (int u = 0; u < 8; ++u) {
    int col = qt * 64 + qgrp + u * 2;
    if (col > LQN - 2) col = LQN - 2;
    f32x2 d = *(const f32x2*)(src + col);
    initL[cc * 65 + qgrp + u * 2]     = d.x;
    initL[cc * 65 + qgrp + u * 2 + 1] = d.y;
  }
  __syncthreads();
  #pragma unroll
  for (int r = 0; r < 4; ++r) {
    const int ql = wv * 16 + qh * 4 + r;
    const int qgl = qt * 64 + ql;
    if (qgl >= LQN) continue;
    const float invl = 1.0f / lrow[r];
    float* dst = out + ((size_t)(b * LQN + qgl)) * CC + h * 64;
    #pragma unroll
    for (int dt = 0; dt < 4; ++dt)
      dst[dt * 16 + r0] = o[dt][r] * invl + initL[(dt * 16 + r0) * 65 + ql];
  }
}

// ---------------- Kernel 2: causal flash attention + residual ----------------
// Pairing: block pi owns Q-tiles hi=31-pi, lo=pi -> 33 tile-computes each,
// shared K/V staging. 1024 equal blocks = 4/CU, no tail.
// K/V double-buffered in LDS via global_load_lds with pre-swizzled per-lane
// SOURCE addresses (LDS dest linear). One __syncthreads per tile; its vmcnt
// drain targets loads issued a full compute-phase earlier.
__global__ __launch_bounds__(256, 4) void attn_kernel(
    const unsigned short* __restrict__ qg, const unsigned short* __restrict__ kg,
    const unsigned short* __restrict__ vg, const float* __restrict__ initw,
    float* __restrict__ out)
{
  __shared__ __align__(16) unsigned short KV[2][8192]; // buf: K [0,4096) V [4096,8192)
  __shared__ __align__(16) unsigned short Pb[4][1024];

  const int pi = blockIdx.x;            // 0..15
  const int hi = 31 - pi, lo = pi;
  const int bh = blockIdx.y;
  const int b = bh >> 3, h = bh & 7;
  const int tid = threadIdx.x, lane = tid & 63, wv = tid >> 6;
  const int r0 = lane & 15, qh = lane >> 4;

  const size_t kqbase = (size_t)bh * LQN * DD;
  const size_t vbase  = ((size_t)(b * CC + h * 64)) * LL;

  // per-lane pre-swizzled staging sources (tile 0); dest is linear in LDS.
  // LDS halfword slot lane*8 of chunk ch holds row r=ch*8+(lane>>3),
  // d-chunk c=(lane&7)^((lane>>3)&7)  ==> matches reader swizzle (c^ (r&7)).
  const int l8 = lane >> 3, c8s = lane & 7;
  const int csw = c8s ^ (l8 & 7);
  const unsigned short* kSrc = kg + kqbase + (size_t)(wv * 16 + l8) * DD + csw * 8;
  const unsigned short* vSrc = vg + vbase  + (size_t)(wv * 16 + l8) * LL + csw * 8;

  // Q fragments for both tiles
  b16x8 aQ0h, aQ1h, aQ0l, aQ1l;
  {
    int qrow = hi * 64 + wv * 16 + r0; if (qrow > LQN - 1) qrow = LQN - 1;
    const unsigned short* qp = qg + kqbase + (size_t)qrow * DD;
    aQ0h = *(const b16x8*)(qp + qh * 8);
    aQ1h = *(const b16x8*)(qp + 32 + qh * 8);
    qrow = lo * 64 + wv * 16 + r0;
    qp = qg + kqbase + (size_t)qrow * DD;
    aQ0l = *(const b16x8*)(qp + qh * 8);
    aQ1l = *(const b16x8*)(qp + 32 + qh * 8);
  }

  const f32x4 zero4 = {0.f, 0.f, 0.f, 0.f};
  f32x4 oh[4], ol[4];
  float mh[4], ml[4], lh[4], llr[4];
  #pragma unroll
  for (int dt = 0; dt < 4; ++dt) { oh[dt] = zero4; ol[dt] = zero4; }
  #pragma unroll
  for (int r = 0; r < 4; ++r) { mh[r] = -1e30f; ml[r] = -1e30f; lh[r] = 0.f; llr[r] = 0.f; }

  int bi = 0;
  issue_tile(kSrc, vSrc, &KV[0][wv * 1024], &KV[0][4096 + wv * 1024]);
  for (int kt = 0; kt <= hi; ++kt) {
    __syncthreads();   // drains this tile's loads (issued last iter); guards buf reuse
    if (kt < hi)
      issue_tile(kSrc, vSrc, &KV[bi ^ 1][wv * 1024], &KV[bi ^ 1][4096 + wv * 1024]);
    attn_tile(&KV[bi][0], &KV[bi][4096], Pb[wv], hi, kt, wv, r0, qh,
              aQ0h, aQ1h, oh, mh, lh);
    if (kt <= lo)
      attn_tile(&KV[bi][0], &KV[bi][4096], Pb[wv], lo, kt, wv, r0, qh,
                aQ0l, aQ1l, ol, ml, llr);
    bi ^= 1;
  }

  attn_epilogue(&KV[0][0], initw, out, b, h, hi, tid, wv, r0, qh, oh, lh);
  attn_epilogue(&KV[0][0], initw, out, b, h, lo, tid, wv, r0, qh, ol, llr);
}

// ---------------- Kernel 3: LayerNorm over C, in-place on d_out --------------
__global__ __launch_bounds__(256) void ln_kernel(
    const float* __restrict__ gamma, const float* __restrict__ beta,
    float* __restrict__ out)
{
  const int row = blockIdx.x * 4 + ((int)threadIdx.x >> 6);
  const int lane = threadIdx.x & 63;
  if (row >= 8 * LQN) return;
  float* p = out + (size_t)row * CC;
  f32x4 x0 = *(const f32x4*)(p + lane * 8);
  f32x4 x1 = *(const f32x4*)(p + lane * 8 + 4);
  float s  = x0.x + x0.y + x0.z + x0.w + x1.x + x1.y + x1.z + x1.w;
  float sq = x0.x*x0.x + x0.y*x0.y + x0.z*x0.z + x0.w*x0.w
           + x1.x*x1.x + x1.y*x1.y + x1.z*x1.z + x1.w*x1.w;
  #pragma unroll
  for (int mm = 1; mm <= 32; mm <<= 1) {
    s  += __shfl_xor(s, mm);
    sq += __shfl_xor(sq, mm);
  }
  const float mu = s * (1.f / 512.f);
  const float var = sq * (1.f / 512.f) - mu * mu;
  const float rstd = rsqrtf(var + 1e-5f);
  f32x4 g0 = *(const f32x4*)(gamma + lane * 8);
  f32x4 g1 = *(const f32x4*)(gamma + lane * 8 + 4);
  f32x4 b0 = *(const f32x4*)(beta + lane * 8);
  f32x4 b1 = *(const f32x4*)(beta + lane * 8 + 4);
  x0 = (x0 - mu) * rstd * g0 + b0;
  x1 = (x1 - mu) * rstd * g1 + b1;
  *(f32x4*)(p + lane * 8)     = x0;
  *(f32x4*)(p + lane * 8 + 4) = x1;
}

extern "C" void kernel_launch(void* const* d_in, const int* in_sizes, int n_in,
                              void* d_out, int out_size, void* d_ws, size_t ws_size,
                              hipStream_t stream)
{
  const float* input = (const float*)d_in[0];
  const float* initw = (const float*)d_in[1];
  const float* qw    = (const float*)d_in[2];
  const float* kw    = (const float*)d_in[3];
  const float* vw    = (const float*)d_in[4];
  const float* gamma = (const float*)d_in[5];
  const float* beta  = (const float*)d_in[6];
  float* outp = (float*)d_out;

  unsigned short* q = (unsigned short*)d_ws;
  unsigned short* k = q + (16u * 1024u * 1024u / 2u);
  unsigned short* v = q + (32u * 1024u * 1024u / 2u);

  hipLaunchKernelGGL(conv_qkv_kernel, dim3(16, 8, 8), dim3(256), 0, stream,
                     input, qw, kw, vw, q, k, v);
  hipLaunchKernelGGL(attn_kernel, dim3(16, 64), dim3(256), 0, stream,
                     q, k, v, initw, outp);
  hipLaunchKernelGGL(ln_kernel, dim3(4092), dim3(256), 0, stream,
                     gamma, beta, outp);
}

// Round 5
// 189.090 us; speedup vs baseline: 2.2460x; 1.7754x over previous
//
#include <hip/hip_runtime.h>

#define LQN 2046
#define LL  2048
#define CC  512
#define DD  64

typedef float  f32x4 __attribute__((ext_vector_type(4)));
typedef float  f32x2 __attribute__((ext_vector_type(2)));
typedef __bf16 b16x8 __attribute__((ext_vector_type(8)));
typedef unsigned int u32x4 __attribute__((ext_vector_type(4)));

static __device__ __forceinline__ unsigned short f2bf(float f) {
  union { float f; unsigned u; } v; v.f = f;
  return (unsigned short)((v.u + 0x7fffu + ((v.u >> 16) & 1u)) >> 16);
}

static __device__ __forceinline__ f32x4 mfma16(b16x8 a, b16x8 b, f32x4 c) {
  return __builtin_amdgcn_mfma_f32_16x16x32_bf16(a, b, c, 0, 0, 0);
}

// async global->LDS, 16B per lane; LDS dest = wave-uniform base + lane*16
static __device__ __forceinline__ void glds16(const unsigned short* g, unsigned short* l) {
  __builtin_amdgcn_global_load_lds(
      (const __attribute__((address_space(1))) unsigned int*)(g),
      (__attribute__((address_space(3))) unsigned int*)(l),
      16, 0, 0);
}

// ---------------- Kernel 1: grouped-conv QKV projections (MFMA) --------------
__global__ __launch_bounds__(256) void conv_qkv_kernel(
    const float* __restrict__ in, const float* __restrict__ qw,
    const float* __restrict__ kw, const float* __restrict__ vw,
    unsigned short* __restrict__ qo, unsigned short* __restrict__ ko,
    unsigned short* __restrict__ vo)
{
  __shared__ __align__(16) unsigned short inT[130 * 72];  // [t][ci] bf16, pad 72
  __shared__ __align__(16) unsigned short buf[128 * 72];  // transpose buffer

  const int tile = blockIdx.x, g = blockIdx.y, b = blockIdx.z;
  const int t0 = tile * 128;
  const int tid = threadIdx.x;
  const int lane = tid & 63;
  const int wv = tid >> 6;
  const int r0 = lane & 15, qh = lane >> 4;

  {
    const int ci = tid & 63, ch = tid >> 6;
    const float* src = in + ((size_t)(b * CC + g * 64 + ci)) * LL;
    #pragma unroll
    for (int i = 0; i < 8; ++i) {
      int t = ch * 32 + i * 4;
      f32x4 d = *(const f32x4*)(src + t0 + t);
      inT[(t + 0) * 72 + ci] = f2bf(d.x);
      inT[(t + 1) * 72 + ci] = f2bf(d.y);
      inT[(t + 2) * 72 + ci] = f2bf(d.z);
      inT[(t + 3) * 72 + ci] = f2bf(d.w);
    }
    if (ch == 0) {
      #pragma unroll
      for (int e = 0; e < 2; ++e) {
        int t = 128 + e;
        int tg = t0 + t; if (tg > LL - 1) tg = LL - 1;
        inT[t * 72 + ci] = f2bf(src[tg]);
      }
    }
  }
  __syncthreads();

  const float* wptr[3] = {qw, kw, vw};
  const f32x4 zero4 = {0.f, 0.f, 0.f, 0.f};

  for (int p = 0; p < 3; ++p) {
    b16x8 aW[6];
    {
      const float* wb = wptr[p] + (size_t)(g * 64 + wv * 16 + r0) * 192;
      #pragma unroll
      for (int kc = 0; kc < 6; ++kc) {
        const int ktap = kc >> 1;
        const int cib = (kc & 1) * 32 + qh * 8;
        union { b16x8 v; unsigned short u[8]; } fr;
        #pragma unroll
        for (int j = 0; j < 8; ++j)
          fr.u[j] = f2bf(wb[(cib + j) * 3 + ktap]);
        aW[kc] = fr.v;
      }
    }
    f32x4 acc[8];
    #pragma unroll
    for (int nt = 0; nt < 8; ++nt) acc[nt] = zero4;
    #pragma unroll
    for (int kc = 0; kc < 6; ++kc) {
      const int radd = kc >> 1;
      const int colh = (kc & 1) * 32 + qh * 8;
      #pragma unroll
      for (int nt = 0; nt < 8; ++nt) {
        const int trow = nt * 16 + r0 + radd;
        b16x8 bI = *(const b16x8*)&inT[trow * 72 + colh];
        acc[nt] = mfma16(aW[kc], bI, acc[nt]);
      }
    }
    __syncthreads();
    if (p < 2) {
      #pragma unroll
      for (int nt = 0; nt < 8; ++nt) {
        const int t = nt * 16 + r0;
        #pragma unroll
        for (int r = 0; r < 4; ++r)
          buf[t * 72 + wv * 16 + qh * 4 + r] = f2bf(acc[nt][r]);
      }
      __syncthreads();
      unsigned short* dst = (p == 0 ? qo : ko) +
          ((size_t)(b * 8 + g) * LQN + t0) * DD;
      #pragma unroll
      for (int it = 0; it < 4; ++it) {
        const int id = it * 256 + tid;
        const int t = id >> 3, c8 = id & 7;
        if (t0 + t < LQN)
          *(u32x4*)(dst + t * DD + c8 * 8) = *(const u32x4*)&buf[t * 72 + c8 * 8];
      }
    } else {
      #pragma unroll
      for (int nt = 0; nt < 8; ++nt) {
        const int t = nt * 16 + r0;
        #pragma unroll
        for (int r = 0; r < 4; ++r)
          buf[(wv * 16 + qh * 4 + r) * 136 + t] = f2bf(acc[nt][r]);
      }
      __syncthreads();
      unsigned short* dst = vo + ((size_t)(b * CC + g * 64)) * LL + t0;
      #pragma unroll
      for (int it = 0; it < 4; ++it) {
        const int id = it * 256 + tid;
        const int row = id >> 4, c16 = id & 15;
        *(u32x4*)(dst + (size_t)row * LL + c16 * 8) =
            *(const u32x4*)&buf[row * 136 + c16 * 8];
      }
    }
    __syncthreads();
  }
}

// ---------------- attention tile compute (forced inline) ---------------------
static __device__ __forceinline__ void attn_tile(
    const unsigned short* __restrict__ Kl, const unsigned short* __restrict__ Vl,
    unsigned short* __restrict__ Pl,
    int qt, int kt, int wv, int r0, int qh,
    b16x8 aQ0, b16x8 aQ1,
    f32x4 (&o)[4], float (&mrow)[4], float (&lrow)[4])
{
  const float SCL = 0.51006979f;  // log2(e)/sqrt(8)
  f32x4 s[4];
  #pragma unroll
  for (int nt = 0; nt < 4; ++nt) {            // S = Q K^T (always 4 row-tiles)
    const int krow = nt * 16 + r0;
    const unsigned short* kr = Kl + krow * 64;
    const int sw = krow & 7;
    b16x8 b0 = *(const b16x8*)(kr + ((qh ^ sw) * 8));
    b16x8 b1 = *(const b16x8*)(kr + (((4 + qh) ^ sw) * 8));
    f32x4 acc = {0.f, 0.f, 0.f, 0.f};
    acc = mfma16(aQ0, b0, acc);
    s[nt] = mfma16(aQ1, b1, acc) * SCL;
  }
  if (kt == qt) {                             // causal mask (local coords)
    #pragma unroll
    for (int nt = 0; nt < 4; ++nt) {
      #pragma unroll
      for (int r = 0; r < 4; ++r) {
        const int rowl = wv * 16 + qh * 4 + r;
        const int coll = nt * 16 + r0;
        if (coll > rowl) s[nt][r] = -1e30f;
      }
    }
  }
  f32x4 corrv;
  #pragma unroll
  for (int r = 0; r < 4; ++r) {
    float s0 = s[0][r], s1 = s[1][r], s2 = s[2][r], s3 = s[3][r];
    float mt = fmaxf(fmaxf(s0, s1), fmaxf(s2, s3));
    #pragma unroll
    for (int mm = 1; mm <= 8; mm <<= 1) mt = fmaxf(mt, __shfl_xor(mt, mm));
    const float mn = fmaxf(mrow[r], mt);
    const float corr = __builtin_amdgcn_exp2f(mrow[r] - mn);
    mrow[r] = mn;
    const float p0 = __builtin_amdgcn_exp2f(s0 - mn);
    const float p1 = __builtin_amdgcn_exp2f(s1 - mn);
    const float p2 = __builtin_amdgcn_exp2f(s2 - mn);
    const float p3 = __builtin_amdgcn_exp2f(s3 - mn);
    float ps = p0 + p1 + p2 + p3;
    #pragma unroll
    for (int mm = 1; mm <= 8; mm <<= 1) ps += __shfl_xor(ps, mm);
    lrow[r] = lrow[r] * corr + ps;
    corrv[r] = corr;
    const int rl = qh * 4 + r;
    const int sw = rl & 7;
    unsigned short* pw = Pl + rl * 64;
    pw[((r0 >> 3) ^ sw) * 8 + (r0 & 7)]        = f2bf(p0);
    pw[(((16 + r0) >> 3) ^ sw) * 8 + (r0 & 7)] = f2bf(p1);
    pw[(((32 + r0) >> 3) ^ sw) * 8 + (r0 & 7)] = f2bf(p2);
    pw[(((48 + r0) >> 3) ^ sw) * 8 + (r0 & 7)] = f2bf(p3);
  }
  #pragma unroll
  for (int dt = 0; dt < 4; ++dt) o[dt] *= corrv;
  #pragma unroll
  for (int kc = 0; kc < 2; ++kc) {            // O += P V
    b16x8 aP = *(const b16x8*)(Pl + r0 * 64 + (((kc * 4 + qh) ^ (r0 & 7)) * 8));
    #pragma unroll
    for (int dt = 0; dt < 4; ++dt) {
      const int vrow = dt * 16 + r0;
      b16x8 bv = *(const b16x8*)(Vl + vrow * 64 + (((kc * 4 + qh) ^ (vrow & 7)) * 8));
      o[dt] = mfma16(aP, bv, o[dt]);
    }
  }
}

static __device__ __forceinline__ void issue_tile(
    const unsigned short*& kSrc, const unsigned short*& vSrc,
    unsigned short* kDst, unsigned short* vDst)
{
  glds16(kSrc,          kDst);
  glds16(kSrc + 8 * DD, kDst + 512);
  glds16(vSrc,          vDst);
  glds16(vSrc + 8 * LL, vDst + 512);
  kSrc += 64 * DD;   // next kv tile: +64 rows
  vSrc += 64;        // next kv tile: +64 columns
}

static __device__ __forceinline__ void attn_epilogue(
    unsigned short* smem, const float* __restrict__ initw,
    float* __restrict__ out, int b, int h, int qt,
    int tid, int wv, int r0, int qh,
    f32x4 (&o)[4], float (&lrow)[4])
{
  __syncthreads();
  float* initL = (float*)smem;     // [64 c][65]
  const int cc = tid >> 2, qgrp = (tid & 3) * 16;
  const float* src = initw + (size_t)(b * CC + h * 64 + cc) * LQN;
  #pragma unroll
  for (int u = 0; u < 8; ++u) {
    int col = qt * 64 + qgrp + u * 2;
    if (col > LQN - 2) col = LQN - 2;
    f32x2 d = *(const f32x2*)(src + col);
    initL[cc * 65 + qgrp + u * 2]     = d.x;
    initL[cc * 65 + qgrp + u * 2 + 1] = d.y;
  }
  __syncthreads();
  #pragma unroll
  for (int r = 0; r < 4; ++r) {
    const int ql = wv * 16 + qh * 4 + r;
    const int qgl = qt * 64 + ql;
    if (qgl >= LQN) continue;
    const float invl = 1.0f / lrow[r];
    float* dst = out + ((size_t)(b * LQN + qgl)) * CC + h * 64;
    #pragma unroll
    for (int dt = 0; dt < 4; ++dt)
      dst[dt * 16 + r0] = o[dt][r] * invl + initL[(dt * 16 + r0) * 65 + ql];
  }
}

// ---------------- Kernel 2: causal flash attention + residual ----------------
// Pairing: block pi owns Q-tiles hi=31-pi, lo=pi -> 33 tile-computes each,
// shared K/V staging. 1024 equal blocks, no tail. K/V double-buffered via
// global_load_lds with pre-swizzled per-lane SOURCE addresses (LDS dest
// linear). One __syncthreads per tile.
// NOTE: plain __launch_bounds__(256) — the (256,4) variant caps the register
// file at 128 (arch+acc) and spills ~350 MB/launch of scratch (round-3 PMC).
__global__ __launch_bounds__(256) void attn_kernel(
    const unsigned short* __restrict__ qg, const unsigned short* __restrict__ kg,
    const unsigned short* __restrict__ vg, const float* __restrict__ initw,
    float* __restrict__ out)
{
  __shared__ __align__(16) unsigned short KV[2][8192]; // buf: K [0,4096) V [4096,8192)
  __shared__ __align__(16) unsigned short Pb[4][1024];

  const int pi = blockIdx.x;            // 0..15
  const int hi = 31 - pi, lo = pi;
  const int bh = blockIdx.y;
  const int b = bh >> 3, h = bh & 7;
  const int tid = threadIdx.x, lane = tid & 63, wv = tid >> 6;
  const int r0 = lane & 15, qh = lane >> 4;

  const size_t kqbase = (size_t)bh * LQN * DD;
  const size_t vbase  = ((size_t)(b * CC + h * 64)) * LL;

  // per-lane pre-swizzled staging sources (tile 0); dest is linear in LDS.
  const int l8 = lane >> 3, c8s = lane & 7;
  const int csw = c8s ^ l8;
  const unsigned short* kSrc = kg + kqbase + (size_t)(wv * 16 + l8) * DD + csw * 8;
  const unsigned short* vSrc = vg + vbase  + (size_t)(wv * 16 + l8) * LL + csw * 8;

  // Q fragments for both tiles
  b16x8 aQ0h, aQ1h, aQ0l, aQ1l;
  {
    int qrow = hi * 64 + wv * 16 + r0; if (qrow > LQN - 1) qrow = LQN - 1;
    const unsigned short* qp = qg + kqbase + (size_t)qrow * DD;
    aQ0h = *(const b16x8*)(qp + qh * 8);
    aQ1h = *(const b16x8*)(qp + 32 + qh * 8);
    qrow = lo * 64 + wv * 16 + r0;
    qp = qg + kqbase + (size_t)qrow * DD;
    aQ0l = *(const b16x8*)(qp + qh * 8);
    aQ1l = *(const b16x8*)(qp + 32 + qh * 8);
  }

  const f32x4 zero4 = {0.f, 0.f, 0.f, 0.f};
  f32x4 oh[4], ol[4];
  float mh[4], ml[4], lh[4], llr[4];
  #pragma unroll
  for (int dt = 0; dt < 4; ++dt) { oh[dt] = zero4; ol[dt] = zero4; }
  #pragma unroll
  for (int r = 0; r < 4; ++r) { mh[r] = -1e30f; ml[r] = -1e30f; lh[r] = 0.f; llr[r] = 0.f; }

  int bi = 0;
  issue_tile(kSrc, vSrc, &KV[0][wv * 1024], &KV[0][4096 + wv * 1024]);
  for (int kt = 0; kt <= hi; ++kt) {
    __syncthreads();   // drains this tile's loads (issued last iter); guards buf reuse
    if (kt < hi)
      issue_tile(kSrc, vSrc, &KV[bi ^ 1][wv * 1024], &KV[bi ^ 1][4096 + wv * 1024]);
    attn_tile(&KV[bi][0], &KV[bi][4096], Pb[wv], hi, kt, wv, r0, qh,
              aQ0h, aQ1h, oh, mh, lh);
    if (kt <= lo)
      attn_tile(&KV[bi][0], &KV[bi][4096], Pb[wv], lo, kt, wv, r0, qh,
                aQ0l, aQ1l, ol, ml, llr);
    bi ^= 1;
  }

  attn_epilogue(&KV[0][0], initw, out, b, h, hi, tid, wv, r0, qh, oh, lh);
  attn_epilogue(&KV[0][0], initw, out, b, h, lo, tid, wv, r0, qh, ol, llr);
}

// ---------------- Kernel 3: LayerNorm over C, in-place on d_out --------------
__global__ __launch_bounds__(256) void ln_kernel(
    const float* __restrict__ gamma, const float* __restrict__ beta,
    float* __restrict__ out)
{
  const int row = blockIdx.x * 4 + ((int)threadIdx.x >> 6);
  const int lane = threadIdx.x & 63;
  if (row >= 8 * LQN) return;
  float* p = out + (size_t)row * CC;
  f32x4 x0 = *(const f32x4*)(p + lane * 8);
  f32x4 x1 = *(const f32x4*)(p + lane * 8 + 4);
  float s  = x0.x + x0.y + x0.z + x0.w + x1.x + x1.y + x1.z + x1.w;
  float sq = x0.x*x0.x + x0.y*x0.y + x0.z*x0.z + x0.w*x0.w
           + x1.x*x1.x + x1.y*x1.y + x1.z*x1.z + x1.w*x1.w;
  #pragma unroll
  for (int mm = 1; mm <= 32; mm <<= 1) {
    s  += __shfl_xor(s, mm);
    sq += __shfl_xor(sq, mm);
  }
  const float mu = s * (1.f / 512.f);
  const float var = sq * (1.f / 512.f) - mu * mu;
  const float rstd = rsqrtf(var + 1e-5f);
  f32x4 g0 = *(const f32x4*)(gamma + lane * 8);
  f32x4 g1 = *(const f32x4*)(gamma + lane * 8 + 4);
  f32x4 b0 = *(const f32x4*)(beta + lane * 8);
  f32x4 b1 = *(const f32x4*)(beta + lane * 8 + 4);
  x0 = (x0 - mu) * rstd * g0 + b0;
  x1 = (x1 - mu) * rstd * g1 + b1;
  *(f32x4*)(p + lane * 8)     = x0;
  *(f32x4*)(p + lane * 8 + 4) = x1;
}

extern "C" void kernel_launch(void* const* d_in, const int* in_sizes, int n_in,
                              void* d_out, int out_size, void* d_ws, size_t ws_size,
                              hipStream_t stream)
{
  const float* input = (const float*)d_in[0];
  const float* initw = (const float*)d_in[1];
  const float* qw    = (const float*)d_in[2];
  const float* kw    = (const float*)d_in[3];
  const float* vw    = (const float*)d_in[4];
  const float* gamma = (const float*)d_in[5];
  const float* beta  = (const float*)d_in[6];
  float* outp = (float*)d_out;

  unsigned short* q = (unsigned short*)d_ws;
  unsigned short* k = q + (16u * 1024u * 1024u / 2u);
  unsigned short* v = q + (32u * 1024u * 1024u / 2u);

  hipLaunchKernelGGL(conv_qkv_kernel, dim3(16, 8, 8), dim3(256), 0, stream,
                     input, qw, kw, vw, q, k, v);
  hipLaunchKernelGGL(attn_kernel, dim3(16, 64), dim3(256), 0, stream,
                     q, k, v, initw, outp);
  hipLaunchKernelGGL(ln_kernel, dim3(4092), dim3(256), 0, stream,
                     gamma, beta, outp);
}

// Round 6
// 150.393 us; speedup vs baseline: 2.8238x; 1.2573x over previous
//
#include <hip/hip_runtime.h>

#define LQN 2046
#define LL  2048
#define CC  512
#define DD  64

typedef float  f32x4 __attribute__((ext_vector_type(4)));
typedef float  f32x2 __attribute__((ext_vector_type(2)));
typedef __bf16 b16x8 __attribute__((ext_vector_type(8)));
typedef unsigned int u32x4 __attribute__((ext_vector_type(4)));
typedef unsigned int u32x2 __attribute__((ext_vector_type(2)));

static __device__ __forceinline__ unsigned short f2bf(float f) {
  union { float f; unsigned u; } v; v.f = f;
  return (unsigned short)((v.u + 0x7fffu + ((v.u >> 16) & 1u)) >> 16);
}

static __device__ __forceinline__ unsigned cvtpk(float lo, float hi) {
  unsigned r;
  asm("v_cvt_pk_bf16_f32 %0, %1, %2" : "=v"(r) : "v"(lo), "v"(hi));
  return r;
}

static __device__ __forceinline__ f32x4 mfma16(b16x8 a, b16x8 b, f32x4 c) {
  return __builtin_amdgcn_mfma_f32_16x16x32_bf16(a, b, c, 0, 0, 0);
}

// async global->LDS, 16B per lane; LDS dest = wave-uniform base + lane*16
static __device__ __forceinline__ void glds16(const unsigned short* g, unsigned short* l) {
  __builtin_amdgcn_global_load_lds(
      (const __attribute__((address_space(1))) unsigned int*)(g),
      (__attribute__((address_space(3))) unsigned int*)(l),
      16, 0, 0);
}

// ---------------- Kernel 1: grouped-conv QKV projections (MFMA) --------------
// Q is pre-scaled by log2(e)/sqrt(H) so attention scores land in exp2 domain.
__global__ __launch_bounds__(256) void conv_qkv_kernel(
    const float* __restrict__ in, const float* __restrict__ qw,
    const float* __restrict__ kw, const float* __restrict__ vw,
    unsigned short* __restrict__ qo, unsigned short* __restrict__ ko,
    unsigned short* __restrict__ vo)
{
  __shared__ __align__(16) unsigned short inT[130 * 72];  // [t][ci] bf16, pad 72
  __shared__ __align__(16) unsigned short buf[128 * 72];  // transpose buffer

  const int tile = blockIdx.x, g = blockIdx.y, b = blockIdx.z;
  const int t0 = tile * 128;
  const int tid = threadIdx.x;
  const int lane = tid & 63;
  const int wv = tid >> 6;
  const int r0 = lane & 15, qh = lane >> 4;

  {
    const int ci = tid & 63, ch = tid >> 6;
    const float* src = in + ((size_t)(b * CC + g * 64 + ci)) * LL;
    #pragma unroll
    for (int i = 0; i < 8; ++i) {
      int t = ch * 32 + i * 4;
      f32x4 d = *(const f32x4*)(src + t0 + t);
      inT[(t + 0) * 72 + ci] = f2bf(d.x);
      inT[(t + 1) * 72 + ci] = f2bf(d.y);
      inT[(t + 2) * 72 + ci] = f2bf(d.z);
      inT[(t + 3) * 72 + ci] = f2bf(d.w);
    }
    if (ch == 0) {
      #pragma unroll
      for (int e = 0; e < 2; ++e) {
        int t = 128 + e;
        int tg = t0 + t; if (tg > LL - 1) tg = LL - 1;
        inT[t * 72 + ci] = f2bf(src[tg]);
      }
    }
  }
  __syncthreads();

  const float* wptr[3] = {qw, kw, vw};
  const f32x4 zero4 = {0.f, 0.f, 0.f, 0.f};

  for (int p = 0; p < 3; ++p) {
    b16x8 aW[6];
    {
      const float* wb = wptr[p] + (size_t)(g * 64 + wv * 16 + r0) * 192;
      #pragma unroll
      for (int kc = 0; kc < 6; ++kc) {
        const int ktap = kc >> 1;
        const int cib = (kc & 1) * 32 + qh * 8;
        union { b16x8 v; unsigned short u[8]; } fr;
        #pragma unroll
        for (int j = 0; j < 8; ++j)
          fr.u[j] = f2bf(wb[(cib + j) * 3 + ktap]);
        aW[kc] = fr.v;
      }
    }
    f32x4 acc[8];
    #pragma unroll
    for (int nt = 0; nt < 8; ++nt) acc[nt] = zero4;
    #pragma unroll
    for (int kc = 0; kc < 6; ++kc) {
      const int radd = kc >> 1;
      const int colh = (kc & 1) * 32 + qh * 8;
      #pragma unroll
      for (int nt = 0; nt < 8; ++nt) {
        const int trow = nt * 16 + r0 + radd;
        b16x8 bI = *(const b16x8*)&inT[trow * 72 + colh];
        acc[nt] = mfma16(aW[kc], bI, acc[nt]);
      }
    }
    __syncthreads();
    if (p < 2) {
      const float qscl = (p == 0) ? 0.51006979f : 1.0f;  // log2(e)/sqrt(8)
      #pragma unroll
      for (int nt = 0; nt < 8; ++nt) {
        const int t = nt * 16 + r0;
        #pragma unroll
        for (int r = 0; r < 4; ++r)
          buf[t * 72 + wv * 16 + qh * 4 + r] = f2bf(acc[nt][r] * qscl);
      }
      __syncthreads();
      unsigned short* dst = (p == 0 ? qo : ko) +
          ((size_t)(b * 8 + g) * LQN + t0) * DD;
      #pragma unroll
      for (int it = 0; it < 4; ++it) {
        const int id = it * 256 + tid;
        const int t = id >> 3, c8 = id & 7;
        if (t0 + t < LQN)
          *(u32x4*)(dst + t * DD + c8 * 8) = *(const u32x4*)&buf[t * 72 + c8 * 8];
      }
    } else {
      #pragma unroll
      for (int nt = 0; nt < 8; ++nt) {
        const int t = nt * 16 + r0;
        #pragma unroll
        for (int r = 0; r < 4; ++r)
          buf[(wv * 16 + qh * 4 + r) * 136 + t] = f2bf(acc[nt][r]);
      }
      __syncthreads();
      unsigned short* dst = vo + ((size_t)(b * CC + g * 64)) * LL + t0;
      #pragma unroll
      for (int it = 0; it < 4; ++it) {
        const int id = it * 256 + tid;
        const int row = id >> 4, c16 = id & 15;
        *(u32x4*)(dst + (size_t)row * LL + c16 * 8) =
            *(const u32x4*)&buf[row * 136 + c16 * 8];
      }
    }
    __syncthreads();
  }
}

// ---------------- attention tile compute (swapped QK^T, in-reg softmax) ------
// S^T = mfma(K,Q): lane (r0,qh) holds S[q=wv*16+r0][kv=nt*16+qh*4+reg].
// Row-softmax = 15-op reg tree + shfl_xor(16,32). P packed via cvt_pk and
// written as 4x ds_write_b64 into the swizzled per-wave P buffer; PV reads
// are unchanged. Q arrives pre-scaled (exp2 domain).
static __device__ __forceinline__ void attn_tile(
    const unsigned short* __restrict__ Kl, const unsigned short* __restrict__ Vl,
    unsigned short* __restrict__ Pl,
    bool diag, int wv, int r0, int qh,
    b16x8 aQ0, b16x8 aQ1,
    f32x4 (&o)[4], float& mrun, float& lrun)
{
  f32x4 s[4];
  #pragma unroll
  for (int nt = 0; nt < 4; ++nt) {            // S^T = K Q
    const int krow = nt * 16 + r0;
    const unsigned short* kr = Kl + krow * 64;
    const int sw = krow & 7;
    b16x8 k0 = *(const b16x8*)(kr + ((qh ^ sw) * 8));
    b16x8 k1 = *(const b16x8*)(kr + (((4 + qh) ^ sw) * 8));
    f32x4 acc = {0.f, 0.f, 0.f, 0.f};
    acc = mfma16(k0, aQ0, acc);
    s[nt] = mfma16(k1, aQ1, acc);
  }
  if (diag) {                                 // causal: mask kv_local > q_local
    const int rowl = wv * 16 + r0;
    #pragma unroll
    for (int nt = 0; nt < 4; ++nt) {
      #pragma unroll
      for (int rr = 0; rr < 4; ++rr)
        if (nt * 16 + qh * 4 + rr > rowl) s[nt][rr] = -1e30f;
    }
  }
  // ---- row max (tree + 2 shfl) ----
  f32x4 m01, m23;
  #pragma unroll
  for (int rr = 0; rr < 4; ++rr) {
    m01[rr] = fmaxf(s[0][rr], s[1][rr]);
    m23[rr] = fmaxf(s[2][rr], s[3][rr]);
  }
  #pragma unroll
  for (int rr = 0; rr < 4; ++rr) m01[rr] = fmaxf(m01[rr], m23[rr]);
  float mt = fmaxf(fmaxf(m01[0], m01[1]), fmaxf(m01[2], m01[3]));
  mt = fmaxf(mt, __shfl_xor(mt, 16));
  mt = fmaxf(mt, __shfl_xor(mt, 32));
  const float mn = fmaxf(mrun, mt);
  const float corr = __builtin_amdgcn_exp2f(mrun - mn);
  mrun = mn;
  // ---- p = exp2(s - m) ----
  #pragma unroll
  for (int nt = 0; nt < 4; ++nt)
    #pragma unroll
    for (int rr = 0; rr < 4; ++rr)
      s[nt][rr] = __builtin_amdgcn_exp2f(s[nt][rr] - mn);
  // ---- row sum (tree + 2 shfl) ----
  f32x4 t01, t23;
  #pragma unroll
  for (int rr = 0; rr < 4; ++rr) {
    t01[rr] = s[0][rr] + s[1][rr];
    t23[rr] = s[2][rr] + s[3][rr];
  }
  #pragma unroll
  for (int rr = 0; rr < 4; ++rr) t01[rr] += t23[rr];
  float sum = (t01[0] + t01[1]) + (t01[2] + t01[3]);
  sum += __shfl_xor(sum, 16);
  sum += __shfl_xor(sum, 32);
  lrun = lrun * corr + sum;
  // ---- pack P (bf16 pairs) and write 4x b64 into swizzled layout ----
  const int xr = r0 & 7;
  unsigned short* pw = Pl + r0 * 64 + (qh & 1) * 4;
  #pragma unroll
  for (int nt = 0; nt < 4; ++nt) {
    u32x2 w;
    w.x = cvtpk(s[nt][0], s[nt][1]);
    w.y = cvtpk(s[nt][2], s[nt][3]);
    *(u32x2*)(pw + (((nt * 2 + (qh >> 1)) ^ xr) * 8)) = w;
  }
  // ---- broadcast corr to accumulator rows, rescale O ----
  #pragma unroll
  for (int rr = 0; rr < 4; ++rr) {
    const float cq = __shfl(corr, qh * 4 + rr);
    o[0][rr] *= cq; o[1][rr] *= cq; o[2][rr] *= cq; o[3][rr] *= cq;
  }
  // ---- O += P V ----
  #pragma unroll
  for (int kc = 0; kc < 2; ++kc) {
    b16x8 aP = *(const b16x8*)(Pl + r0 * 64 + (((kc * 4 + qh) ^ xr) * 8));
    #pragma unroll
    for (int dt = 0; dt < 4; ++dt) {
      const int vrow = dt * 16 + r0;
      b16x8 bv = *(const b16x8*)(Vl + vrow * 64 + (((kc * 4 + qh) ^ (vrow & 7)) * 8));
      o[dt] = mfma16(aP, bv, o[dt]);
    }
  }
}

static __device__ __forceinline__ void issue_tile(
    const unsigned short*& kSrc, const unsigned short*& vSrc,
    unsigned short* kDst, unsigned short* vDst)
{
  glds16(kSrc,          kDst);
  glds16(kSrc + 8 * DD, kDst + 512);
  glds16(vSrc,          vDst);
  glds16(vSrc + 8 * LL, vDst + 512);
  kSrc += 64 * DD;   // next kv tile: +64 rows
  vSrc += 64;        // next kv tile: +64 columns
}

static __device__ __forceinline__ void attn_epilogue(
    unsigned short* smem, const float* __restrict__ initw,
    float* __restrict__ out, int b, int h, int qt,
    int tid, int wv, int r0, int qh,
    f32x4 (&o)[4], float lrun)
{
  __syncthreads();
  float* initL = (float*)smem;     // [64 c][65]
  const int cc = tid >> 2, qgrp = (tid & 3) * 16;
  const float* src = initw + (size_t)(b * CC + h * 64 + cc) * LQN;
  #pragma unroll
  for (int u = 0; u < 8; ++u) {
    int col = qt * 64 + qgrp + u * 2;
    if (col > LQN - 2) col = LQN - 2;
    f32x2 d = *(const f32x2*)(src + col);
    initL[cc * 65 + qgrp + u * 2]     = d.x;
    initL[cc * 65 + qgrp + u * 2 + 1] = d.y;
  }
  __syncthreads();
  #pragma unroll
  for (int r = 0; r < 4; ++r) {
    const float lq = __shfl(lrun, qh * 4 + r);   // l lives at lane r0 == q
    const int ql = wv * 16 + qh * 4 + r;
    const int qgl = qt * 64 + ql;
    if (qgl >= LQN) continue;
    const float invl = 1.0f / lq;
    float* dst = out + ((size_t)(b * LQN + qgl)) * CC + h * 64;
    #pragma unroll
    for (int dt = 0; dt < 4; ++dt)
      dst[dt * 16 + r0] = o[dt][r] * invl + initL[(dt * 16 + r0) * 65 + ql];
  }
}

// ---------------- Kernel 2: causal flash attention + residual ----------------
// Pairing: block pi owns Q-tiles hi=31-pi, lo=pi -> 33 tile-computes each,
// shared K/V staging, double-buffered global_load_lds (pre-swizzled source).
// NOTE: plain __launch_bounds__(256) — (256,4) caps regs at 128 and spills
// ~350 MB/launch (round-3 PMC).
__global__ __launch_bounds__(256) void attn_kernel(
    const unsigned short* __restrict__ qg, const unsigned short* __restrict__ kg,
    const unsigned short* __restrict__ vg, const float* __restrict__ initw,
    float* __restrict__ out)
{
  __shared__ __align__(16) unsigned short KV[2][8192]; // buf: K [0,4096) V [4096,8192)
  __shared__ __align__(16) unsigned short Pb[4][1024];

  const int pi = blockIdx.x;            // 0..15
  const int hi = 31 - pi, lo = pi;
  const int bh = blockIdx.y;
  const int b = bh >> 3, h = bh & 7;
  const int tid = threadIdx.x, lane = tid & 63, wv = tid >> 6;
  const int r0 = lane & 15, qh = lane >> 4;

  const size_t kqbase = (size_t)bh * LQN * DD;
  const size_t vbase  = ((size_t)(b * CC + h * 64)) * LL;

  // per-lane pre-swizzled staging sources (tile 0); dest is linear in LDS.
  const int l8 = lane >> 3, c8s = lane & 7;
  const int csw = c8s ^ l8;
  const unsigned short* kSrc = kg + kqbase + (size_t)(wv * 16 + l8) * DD + csw * 8;
  const unsigned short* vSrc = vg + vbase  + (size_t)(wv * 16 + l8) * LL + csw * 8;

  // Q fragments for both tiles
  b16x8 aQ0h, aQ1h, aQ0l, aQ1l;
  {
    int qrow = hi * 64 + wv * 16 + r0; if (qrow > LQN - 1) qrow = LQN - 1;
    const unsigned short* qp = qg + kqbase + (size_t)qrow * DD;
    aQ0h = *(const b16x8*)(qp + qh * 8);
    aQ1h = *(const b16x8*)(qp + 32 + qh * 8);
    qrow = lo * 64 + wv * 16 + r0;
    qp = qg + kqbase + (size_t)qrow * DD;
    aQ0l = *(const b16x8*)(qp + qh * 8);
    aQ1l = *(const b16x8*)(qp + 32 + qh * 8);
  }

  const f32x4 zero4 = {0.f, 0.f, 0.f, 0.f};
  f32x4 oh[4], ol[4];
  float mh = -1e30f, ml = -1e30f, lh = 0.f, llr = 0.f;
  #pragma unroll
  for (int dt = 0; dt < 4; ++dt) { oh[dt] = zero4; ol[dt] = zero4; }

  int bi = 0;
  issue_tile(kSrc, vSrc, &KV[0][wv * 1024], &KV[0][4096 + wv * 1024]);
  for (int kt = 0; kt <= hi; ++kt) {
    __syncthreads();   // drains this tile's loads (issued last iter); guards buf reuse
    if (kt < hi)
      issue_tile(kSrc, vSrc, &KV[bi ^ 1][wv * 1024], &KV[bi ^ 1][4096 + wv * 1024]);
    attn_tile(&KV[bi][0], &KV[bi][4096], Pb[wv], kt == hi, wv, r0, qh,
              aQ0h, aQ1h, oh, mh, lh);
    if (kt <= lo)
      attn_tile(&KV[bi][0], &KV[bi][4096], Pb[wv], kt == lo, wv, r0, qh,
                aQ0l, aQ1l, ol, ml, llr);
    bi ^= 1;
  }

  attn_epilogue(&KV[0][0], initw, out, b, h, hi, tid, wv, r0, qh, oh, lh);
  attn_epilogue(&KV[0][0], initw, out, b, h, lo, tid, wv, r0, qh, ol, llr);
}

// ---------------- Kernel 3: LayerNorm over C, in-place on d_out --------------
__global__ __launch_bounds__(256) void ln_kernel(
    const float* __restrict__ gamma, const float* __restrict__ beta,
    float* __restrict__ out)
{
  const int row = blockIdx.x * 4 + ((int)threadIdx.x >> 6);
  const int lane = threadIdx.x & 63;
  if (row >= 8 * LQN) return;
  float* p = out + (size_t)row * CC;
  f32x4 x0 = *(const f32x4*)(p + lane * 8);
  f32x4 x1 = *(const f32x4*)(p + lane * 8 + 4);
  float s  = x0.x + x0.y + x0.z + x0.w + x1.x + x1.y + x1.z + x1.w;
  float sq = x0.x*x0.x + x0.y*x0.y + x0.z*x0.z + x0.w*x0.w
           + x1.x*x1.x + x1.y*x1.y + x1.z*x1.z + x1.w*x1.w;
  #pragma unroll
  for (int mm = 1; mm <= 32; mm <<= 1) {
    s  += __shfl_xor(s, mm);
    sq += __shfl_xor(sq, mm);
  }
  const float mu = s * (1.f / 512.f);
  const float var = sq * (1.f / 512.f) - mu * mu;
  const float rstd = rsqrtf(var + 1e-5f);
  f32x4 g0 = *(const f32x4*)(gamma + lane * 8);
  f32x4 g1 = *(const f32x4*)(gamma + lane * 8 + 4);
  f32x4 b0 = *(const f32x4*)(beta + lane * 8);
  f32x4 b1 = *(const f32x4*)(beta + lane * 8 + 4);
  x0 = (x0 - mu) * rstd * g0 + b0;
  x1 = (x1 - mu) * rstd * g1 + b1;
  *(f32x4*)(p + lane * 8)     = x0;
  *(f32x4*)(p + lane * 8 + 4) = x1;
}

extern "C" void kernel_launch(void* const* d_in, const int* in_sizes, int n_in,
                              void* d_out, int out_size, void* d_ws, size_t ws_size,
                              hipStream_t stream)
{
  const float* input = (const float*)d_in[0];
  const float* initw = (const float*)d_in[1];
  const float* qw    = (const float*)d_in[2];
  const float* kw    = (const float*)d_in[3];
  const float* vw    = (const float*)d_in[4];
  const float* gamma = (const float*)d_in[5];
  const float* beta  = (const float*)d_in[6];
  float* outp = (float*)d_out;

  unsigned short* q = (unsigned short*)d_ws;
  unsigned short* k = q + (16u * 1024u * 1024u / 2u);
  unsigned short* v = q + (32u * 1024u * 1024u / 2u);

  hipLaunchKernelGGL(conv_qkv_kernel, dim3(16, 8, 8), dim3(256), 0, stream,
                     input, qw, kw, vw, q, k, v);
  hipLaunchKernelGGL(attn_kernel, dim3(16, 64), dim3(256), 0, stream,
                     q, k, v, initw, outp);
  hipLaunchKernelGGL(ln_kernel, dim3(4092), dim3(256), 0, stream,
                     gamma, beta, outp);
}